// Round 10
// baseline (268.962 us; speedup 1.0000x reference)
//
#include <hip/hip_runtime.h>
#include <hip/hip_bf16.h>

// Problem constants (B=4, T=2048, D=1024, NH=8, NKV=1, HD=128)
#define B_ 4
#define T_ 2048
#define D_ 1024
#define NH_ 8
#define HD_ 128

typedef short short8 __attribute__((ext_vector_type(8)));    // 8 bf16 (4 VGPRs) MFMA frag
typedef float floatx4 __attribute__((ext_vector_type(4)));   // 16x16 MFMA accumulator
typedef float floatx16 __attribute__((ext_vector_type(16))); // 32x32 MFMA accumulator

#if __has_builtin(__builtin_amdgcn_exp2f)
#define EXP2F __builtin_amdgcn_exp2f
#else
#define EXP2F exp2f
#endif
#if __has_builtin(__builtin_amdgcn_rcpf)
#define RCPF __builtin_amdgcn_rcpf
#else
__device__ __forceinline__ float RCPF(float x) { return 1.f / x; }
#endif

// async global->LDS 16B copy (m97 lever); LDS dest must be wave-uniform base
// + lane*16B, which the GEMM staging pattern satisfies by construction.
#if __has_builtin(__builtin_amdgcn_global_load_lds)
#define G2L(gp, lp)                                                        \
  __builtin_amdgcn_global_load_lds(                                        \
      (const __attribute__((address_space(1))) unsigned int*)(gp),         \
      (__attribute__((address_space(3))) unsigned int*)(lp), 16, 0, 0)
#else
#define G2L(gp, lp) (*(uint4*)(lp) = *(const uint4*)(gp))
#endif

__device__ __forceinline__ unsigned short f2b(float f) {
  union { float fl; unsigned int i; } v; v.fl = f;
  unsigned int r = v.i + 0x7fffu + ((v.i >> 16) & 1u);  // RNE, non-NaN inputs
  return (unsigned short)(r >> 16);
}
// pack two f32 -> two bf16 (round-to-nearest): low16 = a, high16 = b
__device__ __forceinline__ unsigned int pack_bf16(float a, float b) {
  unsigned int ua = __float_as_uint(a) + 0x8000u;
  unsigned int ub = __float_as_uint(b) + 0x8000u;
  return (ua >> 16) | (ub & 0xffff0000u);
}
__device__ __forceinline__ float blo(unsigned int u) { return __uint_as_float(u << 16); }
__device__ __forceinline__ float bhi(unsigned int u) { return __uint_as_float(u & 0xffff0000u); }

// ---------------------------------------------------------------------------
// One-shot f32 -> bf16 convert of x|Wq|Wk|Wv|Wo into a contiguous bf16 blob.
// ---------------------------------------------------------------------------
__global__ __launch_bounds__(256) void cvt_kernel(
    const float* __restrict__ x,  const float* __restrict__ wq,
    const float* __restrict__ wk, const float* __restrict__ wv,
    const float* __restrict__ wo, unsigned short* __restrict__ dst)
{
  size_t i = ((size_t)blockIdx.x * 256 + threadIdx.x) * 8;
  const float* src; size_t off;
  if      (i <  8388608u) { src = x;  off = i; }
  else if (i <  9437184u) { src = wq; off = i - 8388608u; }
  else if (i <  9568256u) { src = wk; off = i - 9437184u; }
  else if (i <  9699328u) { src = wv; off = i - 9568256u; }
  else                    { src = wo; off = i - 9699328u; }
  float4 a = *(const float4*)(src + off);
  float4 b = *(const float4*)(src + off + 4);
  uint4 o;
  o.x = pack_bf16(a.x, a.y); o.y = pack_bf16(a.z, a.w);
  o.z = pack_bf16(b.x, b.y); o.w = pack_bf16(b.z, b.w);
  *(uint4*)(dst + i) = o;
}

// ---------------------------------------------------------------------------
// 128x128-tile GEMM body, C = A * B^T, K=1024, bf16 in, fp32 accumulate.
// ROUND-4 single-buffer schedule (proven best; explicit dbuf (r6), fused
// RoPE (r7), fused combine (r8) all regressed).
// ---------------------------------------------------------------------------
template <bool C_F32>
__device__ __forceinline__ void gemm_body_1024(
    const unsigned short* __restrict__ Arow0,
    const unsigned short* __restrict__ Btile,
    void* __restrict__ Cb, int ldC)
{
  __shared__ unsigned short As[128 * 32];
  __shared__ unsigned short Bs[128 * 32];
  const int tid = threadIdx.x;
  const int lane = tid & 63;
  const int w = tid >> 6;
  const int wr = w >> 1, wc = w & 1;
  const int l15 = lane & 15, quad = lane >> 4;

  const unsigned short* a_src = Arow0 + (size_t)(tid >> 2) * 1024 + (tid & 3) * 8;
  const unsigned short* b_src = Btile + (size_t)(tid >> 2) * 1024 + (tid & 3) * 8;
  unsigned short* a_dst = &As[(tid >> 2) * 32 + (tid & 3) * 8];
  unsigned short* b_dst = &Bs[(tid >> 2) * 32 + (tid & 3) * 8];

  floatx4 zero = {0.f, 0.f, 0.f, 0.f};
  floatx4 acc[4][4];
#pragma unroll
  for (int i = 0; i < 4; i++)
#pragma unroll
    for (int j = 0; j < 4; j++) acc[i][j] = zero;

  for (int k0 = 0; k0 < 1024; k0 += 32) {
    __syncthreads();
    G2L(a_src + k0,         a_dst);
    G2L(a_src + 65536 + k0, a_dst + 2048);   // +64 rows
    G2L(b_src + k0,         b_dst);
    G2L(b_src + 65536 + k0, b_dst + 2048);
    __syncthreads();                          // drains vmcnt incl. lds-DMA
    short8 af[4], bfr[4];
#pragma unroll
    for (int i = 0; i < 4; i++)
      af[i] = *(const short8*)&As[(wr * 64 + i * 16 + l15) * 32 + quad * 8];
#pragma unroll
    for (int j = 0; j < 4; j++)
      bfr[j] = *(const short8*)&Bs[(wc * 64 + j * 16 + l15) * 32 + quad * 8];
#pragma unroll
    for (int i = 0; i < 4; i++)
#pragma unroll
      for (int j = 0; j < 4; j++)
        acc[i][j] = __builtin_amdgcn_mfma_f32_16x16x32_bf16(af[i], bfr[j], acc[i][j], 0, 0, 0);
  }
  // epilogue: C row = quad*4+reg, col = lane&15 (verified m89/m91 layout)
#pragma unroll
  for (int i = 0; i < 4; i++)
#pragma unroll
    for (int j = 0; j < 4; j++)
#pragma unroll
      for (int r = 0; r < 4; r++) {
        size_t off = (size_t)(wr * 64 + i * 16 + quad * 4 + r) * ldC + wc * 64 + j * 16 + l15;
        if (C_F32) ((float*)Cb)[off] = acc[i][j][r];
        else ((unsigned short*)Cb)[off] = f2b(acc[i][j][r]);
      }
}

__global__ __launch_bounds__(256) void gemm_qkv_kernel(
    const unsigned short* __restrict__ x,
    const unsigned short* __restrict__ Wq,
    const unsigned short* __restrict__ Wk,
    const unsigned short* __restrict__ Wv,
    unsigned short* __restrict__ q,
    unsigned short* __restrict__ k,
    unsigned short* __restrict__ v)
{
  const int bx = blockIdx.x, by = blockIdx.y;
  const unsigned short* Btile;
  unsigned short* C;
  int ldC, col0;
  if (by < 8) { Btile = Wq + (size_t)by * 128 * 1024; C = q; ldC = 1024; col0 = by * 128; }
  else if (by == 8) { Btile = Wk; C = k; ldC = 128; col0 = 0; }
  else { Btile = Wv; C = v; ldC = 128; col0 = 0; }
  gemm_body_1024<false>(x + (size_t)bx * 128 * 1024, Btile,
                        C + (size_t)bx * 128 * ldC + col0, ldC);
}

__global__ __launch_bounds__(256) void gemm_out_kernel(
    const unsigned short* __restrict__ ao,
    const unsigned short* __restrict__ Wo,
    float* __restrict__ out)
{
  const int bx = blockIdx.x, by = blockIdx.y;
  gemm_body_1024<true>(ao + (size_t)bx * 128 * 1024, Wo + (size_t)by * 128 * 1024,
                       out + (size_t)bx * 128 * 1024 + by * 128, 1024);
}

// ---------------------------------------------------------------------------
// prep: fused vtrans (blocks 0..255) + vectorized RoPE (8 pairs/thread).
// q gets gain*(1/sqrt(HD))/SOFTCAP folded in. (Round-4 proven version.)
// ---------------------------------------------------------------------------
__global__ __launch_bounds__(256) void prep_kernel(
    unsigned short* __restrict__ q,
    unsigned short* __restrict__ k,
    const unsigned short* __restrict__ v,
    unsigned short* __restrict__ vT,
    const float* __restrict__ cosT,
    const float* __restrict__ sinT,
    const float* __restrict__ gain)
{
  __shared__ unsigned short tile[32 * 136];
  const int tid = threadIdx.x;
  if (blockIdx.x < 256) {
    const int b = blockIdx.x >> 6, t0 = (blockIdx.x & 63) * 32;
    for (int u = tid; u < 512; u += 256) {
      int r = u >> 4, c = u & 15;
      *(uint4*)&tile[r * 136 + c * 8] =
          *(const uint4*)(v + ((size_t)(b * T_ + t0 + r)) * 128 + c * 8);
    }
    __syncthreads();
    for (int u = tid; u < 512; u += 256) {
      int d = u >> 2, c = u & 3;
      short8 val;
#pragma unroll
      for (int j = 0; j < 8; j++) val[j] = (short)tile[(c * 8 + j) * 136 + d];
      *(short8*)(vT + ((size_t)(b * 128 + d)) * T_ + t0 + c * 8) = val;
    }
    return;
  }
  int idx = (blockIdx.x - 256) * 256 + tid;   // 0 .. 589823
  unsigned short* ptr;
  size_t base;
  int t, j;
  float g;
  if (idx < 524288) {                         // q: (bt, h, dim-octet j)
    j = idx & 7;
    int h = (idx >> 3) & 7;
    int bt = idx >> 6;
    t = bt & (T_ - 1);
    base = (size_t)bt * 1024 + h * 128 + j * 8;
    ptr = q;
    g = gain[h] * 0.0029462782549439484f;     // (1/sqrt(128))/30
  } else {                                    // k
    int id = idx - 524288;
    j = id & 7;
    int bt = id >> 3;
    t = bt & (T_ - 1);
    base = (size_t)bt * 128 + j * 8;
    ptr = k;
    g = 1.f;
  }
  float4 ca = *(const float4*)&cosT[t * 64 + j * 8];
  float4 cb = *(const float4*)&cosT[t * 64 + j * 8 + 4];
  float4 sa = *(const float4*)&sinT[t * 64 + j * 8];
  float4 sb = *(const float4*)&sinT[t * 64 + j * 8 + 4];
  uint4 lo = *(const uint4*)(ptr + base);
  uint4 hi = *(const uint4*)(ptr + base + 64);
  uint4 olo, ohi;
  {
    float a0 = blo(lo.x), a1 = bhi(lo.x), b0 = blo(hi.x), b1 = bhi(hi.x);
    olo.x = pack_bf16((a0 * ca.x - b0 * sa.x) * g, (a1 * ca.y - b1 * sa.y) * g);
    ohi.x = pack_bf16((a0 * sa.x + b0 * ca.x) * g, (a1 * sa.y + b1 * ca.y) * g);
  }
  {
    float a0 = blo(lo.y), a1 = bhi(lo.y), b0 = blo(hi.y), b1 = bhi(hi.y);
    olo.y = pack_bf16((a0 * ca.z - b0 * sa.z) * g, (a1 * ca.w - b1 * sa.w) * g);
    ohi.y = pack_bf16((a0 * sa.z + b0 * ca.z) * g, (a1 * sa.w + b1 * ca.w) * g);
  }
  {
    float a0 = blo(lo.z), a1 = bhi(lo.z), b0 = blo(hi.z), b1 = bhi(hi.z);
    olo.z = pack_bf16((a0 * cb.x - b0 * sb.x) * g, (a1 * cb.y - b1 * sb.y) * g);
    ohi.z = pack_bf16((a0 * sb.x + b0 * cb.x) * g, (a1 * sb.y + b1 * cb.y) * g);
  }
  {
    float a0 = blo(lo.w), a1 = bhi(lo.w), b0 = blo(hi.w), b1 = bhi(hi.w);
    olo.w = pack_bf16((a0 * cb.z - b0 * sb.z) * g, (a1 * cb.w - b1 * sb.w) * g);
    ohi.w = pack_bf16((a0 * sb.z + b0 * cb.z) * g, (a1 * sb.w + b1 * cb.w) * g);
  }
  *(uint4*)(ptr + base) = olo;
  *(uint4*)(ptr + base + 64) = ohi;
}

// ---------------------------------------------------------------------------
// Flash attention. ROUND 17: 2 k-tiles per barrier epoch (quad-buffer).
// Invariant across 7 prior variants: ~2700 cyc/wave-tile measured vs ~500
// cyc issue work, all pipes <40% busy. The unmodeled cost of that size is
// the barrier-EPOCH overhead (lockstep arrival spread + pipeline refill,
// 34 epochs/pass, only 2 blocks/CU to overlap). Prior rounds changed the
// inside of the epoch; this round halves the NUMBER of epochs: per barrier,
// prefetch the next PAIR of tiles into regs (8x16B, better MLP), compute
// tiles kt and kt+1 from buffer pair bp, write-late the next pair into
// bp^2. NSPLIT=2 makes every tile range even-aligned and even-length
// (seg = 2qb+2), so pairs align with no tail. LDS 4x(8448+10240) = 74.8KB;
// occupancy is register-capped at 2 blocks/CU, so 149.5KB/CU still fits --
// the extra LDS is free. +16 VGPR (prefetch pair), stays in 2-wave band.
// 32x32x16 MFMA, 32 q-rows/wave, in-register softmax + 4 permlane32_swap.
// ---------------------------------------------------------------------------
template <int NSPLIT>
__global__ __launch_bounds__(256, 2) void attn_kernel(
    const unsigned short* __restrict__ q,
    const unsigned short* __restrict__ k,
    const unsigned short* __restrict__ vT,
    unsigned short* __restrict__ ao,
    unsigned short* __restrict__ Opart,
    float* __restrict__ lbuf)
{
  __shared__ unsigned short Ks[4][16 * 264];   // [buf][dimgroup d][key*8 + j]
  __shared__ unsigned short Vts[4][128 * 40];  // [buf][dim][key]

  const int h = blockIdx.y, b = blockIdx.z;
  const int pr   = blockIdx.x / NSPLIT;        // 0..7 (chunk-pair index)
  const int part = blockIdx.x % NSPLIT;
  const int tid = threadIdx.x, lane = tid & 63, w = tid >> 6;
  const int q32 = lane & 31, hi = lane >> 5;

  // K staging: key = tid>>4 (+16), dimgroup = tid&15
  const unsigned short* ksrc =
      k + (size_t)b * T_ * 128 + (size_t)(tid >> 4) * 128 + (tid & 15) * 8;
  const int koff0 = (tid & 15) * 264 + (tid >> 4) * 8;
  const int koff1 = koff0 + 16 * 8;
  // V staging: row = tid>>2 (+64), col8 = tid&3
  const unsigned short* vsrc =
      vT + (size_t)b * 128 * T_ + (size_t)(tid >> 2) * T_ + (tid & 3) * 8;
  const int voff0 = (tid >> 2) * 40 + (tid & 3) * 8;
  const int voff1 = voff0 + 64 * 40;

  for (int pass = 0; pass < 2; pass++) {
    const int qblock = pass ? (15 - pr) : pr;  // 128-row q-chunk index
    const int qw = qblock * 128 + w * 32;      // wave's first q-row
    const int nkt = 4 * qblock + 4;            // even
    const int seg = nkt / NSPLIT;              // even for NSPLIT in {1,2}
    const int ktBeg = part * seg;              // even
    const int ktEnd = ktBeg + seg;

    // Q B-frags: lane holds Q[q=qw+q32][dim = c*16 + 8*hi + j], c=0..7
    short8 qf[8];
    {
      const unsigned short* qrow =
          q + ((size_t)(b * T_ + qw + q32) * NH_ + h) * HD_ + hi * 8;
#pragma unroll
      for (int c = 0; c < 8; c++) qf[c] = *(const short8*)(qrow + c * 16);
    }

    float l_i = 0.f;
    floatx16 acc[4];
#pragma unroll
    for (int dt = 0; dt < 4; dt++)
#pragma unroll
      for (int r = 0; r < 16; r++) acc[dt][r] = 0.f;

    // pass-start barrier: previous pass/prologue reads done before reuse
    __syncthreads();
    // prologue: stage pair (ktBeg, ktBeg+1) into buffers 0,1
#pragma unroll
    for (int s = 0; s < 2; s++) {
      const int kn = ktBeg + s;
      uint4 kr0 = *(const uint4*)(ksrc + (size_t)kn * 4096);
      uint4 kr1 = *(const uint4*)(ksrc + (size_t)kn * 4096 + 2048);
      uint4 vr0 = *(const uint4*)(vsrc + kn * 32);
      uint4 vr1 = *(const uint4*)(vsrc + (size_t)64 * T_ + kn * 32);
      unsigned short* kb = Ks[s];
      unsigned short* vb = Vts[s];
      *(uint4*)(kb + koff0) = kr0; *(uint4*)(kb + koff1) = kr1;
      *(uint4*)(vb + voff0) = vr0; *(uint4*)(vb + voff1) = vr1;
    }

    int bp = 0;                        // current buffer-pair base (0 or 2)
    for (int kt = ktBeg; kt < ktEnd; kt += 2) {
      __syncthreads();                 // publishes buffers bp, bp+1
      // prefetch next pair AFTER the barrier (T14): latency hides under
      // the two computes; write-late consumes before the next barrier.
      uint4 kr0[2], kr1[2], vr0[2], vr1[2];
      const bool more = (kt + 2 < ktEnd);
      if (more) {
#pragma unroll
        for (int s = 0; s < 2; s++) {
          const int kn = kt + 2 + s;
          kr0[s] = *(const uint4*)(ksrc + (size_t)kn * 4096);
          kr1[s] = *(const uint4*)(ksrc + (size_t)kn * 4096 + 2048);
          vr0[s] = *(const uint4*)(vsrc + kn * 32);
          vr1[s] = *(const uint4*)(vsrc + (size_t)64 * T_ + kn * 32);
        }
      }

#pragma unroll
      for (int s = 0; s < 2; s++) {
        const int ktc = kt + s;
        if (ktc * 32 > qw + 31) continue;   // wave-uniform causal skip
        const unsigned short* KsC = Ks[bp + s];
        const unsigned short* VtC = Vts[bp + s];
        // S^T = K Q^T, one 32x32 tile, K-dim = 128 = 8 chained MFMA32
        floatx16 st;
#pragma unroll
        for (int r = 0; r < 16; r++) st[r] = 0.f;
#pragma unroll
        for (int c = 0; c < 8; c++) {
          short8 kf = *(const short8*)&KsC[(2 * c + hi) * 264 + q32 * 8];
          st = __builtin_amdgcn_mfma_f32_32x32x16_bf16(kf, qf[c], st, 0, 0, 0);
        }
        // fused softcap+softmax numerator (fixed m=30), all in registers
        float rs = 0.f;
        unsigned int A[8];
        if (ktc * 32 + 31 <= qw) {     // fully unmasked (most iterations)
          float pv[16];
#pragma unroll
          for (int r = 0; r < 16; r++) {
            float s2 = st[r];
            float e = EXP2F(2.8853901f * s2);
            float u = RCPF(e + 1.f);
            float p = EXP2F(-86.561707f * u);
            pv[r] = p;
            rs += p;
          }
#pragma unroll
          for (int m = 0; m < 8; m++) A[m] = pack_bf16(pv[2 * m], pv[2 * m + 1]);
        } else {                       // boundary tile: apply causal mask
          const int qrow = qw + q32;
          float pv[16];
#pragma unroll
          for (int r = 0; r < 16; r++) {
            float s2 = st[r];
            float e = EXP2F(2.8853901f * s2);
            float u = RCPF(e + 1.f);
            float p = EXP2F(-86.561707f * u);
            int key = ktc * 32 + (r & 3) + 8 * (r >> 2) + 4 * hi;
            p = (key <= qrow) ? p : 0.f;
            pv[r] = p;
            rs += p;
          }
#pragma unroll
          for (int m = 0; m < 8; m++) A[m] = pack_bf16(pv[2 * m], pv[2 * m + 1]);
        }
        // build PV B-frags via 4 permlane32 swaps (round-12 derivation)
        unsigned int a0 = A[0], a1 = A[1], a2 = A[2], a3 = A[3];
        unsigned int a4 = A[4], a5 = A[5], a6 = A[6], a7 = A[7];
        asm("v_permlane32_swap_b32 %0, %1" : "+v"(a0), "+v"(a2));
        asm("v_permlane32_swap_b32 %0, %1" : "+v"(a1), "+v"(a3));
        asm("v_permlane32_swap_b32 %0, %1" : "+v"(a4), "+v"(a6));
        asm("v_permlane32_swap_b32 %0, %1" : "+v"(a5), "+v"(a7));
        uint4 u0; u0.x = a0; u0.y = a1; u0.z = a2; u0.w = a3;
        uint4 u1; u1.x = a4; u1.y = a5; u1.z = a6; u1.w = a7;
        short8 pf0 = *(short8*)&u0;   // keys 0-15 B-frag
        short8 pf1 = *(short8*)&u1;   // keys 16-31 B-frag
        l_i += rs + __shfl_xor(rs, 32);
        // O^T += V^T P^T: 4 d-tiles x 2 key-halves
#pragma unroll
        for (int dt = 0; dt < 4; dt++) {
          short8 v0 = *(const short8*)&VtC[(dt * 32 + q32) * 40 + hi * 8];
          short8 v1 = *(const short8*)&VtC[(dt * 32 + q32) * 40 + 16 + hi * 8];
          acc[dt] = __builtin_amdgcn_mfma_f32_32x32x16_bf16(v0, pf0, acc[dt], 0, 0, 0);
          acc[dt] = __builtin_amdgcn_mfma_f32_32x32x16_bf16(v1, pf1, acc[dt], 0, 0, 0);
        }
      }

      if (more) {                      // write-late: stage next pair
#pragma unroll
        for (int s = 0; s < 2; s++) {
          unsigned short* kb = Ks[(bp ^ 2) + s];
          unsigned short* vb = Vts[(bp ^ 2) + s];
          *(uint4*)(kb + koff0) = kr0[s]; *(uint4*)(kb + koff1) = kr1[s];
          *(uint4*)(vb + voff0) = vr0[s]; *(uint4*)(vb + voff1) = vr1[s];
        }
      }
      bp ^= 2;
    }

    // epilogue: lane q=q32; acc[dt][r] = O^T[dim=dt*32+(r&3)+8(r>>2)+4hi][q]
    {
      const size_t rowidx = (size_t)(b * T_ + qw + q32) * NH_ + h;
      if (NSPLIT == 1) {
        float linv = 1.f / l_i;
        unsigned short* aop = ao + rowidx * HD_;
#pragma unroll
        for (int dt = 0; dt < 4; dt++)
#pragma unroll
          for (int rg = 0; rg < 4; rg++) {
            uint2 o;
            o.x = pack_bf16(acc[dt][4 * rg + 0] * linv, acc[dt][4 * rg + 1] * linv);
            o.y = pack_bf16(acc[dt][4 * rg + 2] * linv, acc[dt][4 * rg + 3] * linv);
            *(uint2*)(aop + dt * 32 + rg * 8 + hi * 4) = o;
          }
      } else {
        unsigned short* dst =
            ((part == NSPLIT - 1) ? ao : Opart + (size_t)part * 8388608u) +
            rowidx * HD_;
#pragma unroll
        for (int dt = 0; dt < 4; dt++)
#pragma unroll
          for (int rg = 0; rg < 4; rg++) {
            uint2 o;
            o.x = pack_bf16(acc[dt][4 * rg + 0], acc[dt][4 * rg + 1]);
            o.y = pack_bf16(acc[dt][4 * rg + 2], acc[dt][4 * rg + 3]);
            *(uint2*)(dst + dt * 32 + rg * 8 + hi * 4) = o;
          }
        if (hi == 0) lbuf[(size_t)part * 65536u + rowidx] = l_i;
      }
    }
  }
}

// ao = (sum of partials + ao) / (sum of l), 8 bf16 elems per thread
template <int NSPLIT>
__global__ __launch_bounds__(256) void combine_kernel(
    const unsigned short* __restrict__ Opart,
    const float* __restrict__ lbuf,
    unsigned short* __restrict__ ao)
{
  size_t i = ((size_t)blockIdx.x * 256 + threadIdx.x) * 8;
  size_t r = i >> 7;                          // (b*T+t)*NH+h
  float ls = 0.f;
#pragma unroll
  for (int p = 0; p < NSPLIT; p++) ls += lbuf[(size_t)p * 65536u + r];
  float linv = RCPF(ls);
  uint4 c = *(const uint4*)(ao + i);
  float v0 = blo(c.x), v1 = bhi(c.x), v2 = blo(c.y), v3 = bhi(c.y);
  float v4 = blo(c.z), v5 = bhi(c.z), v6 = blo(c.w), v7 = bhi(c.w);
#pragma unroll
  for (int p = 0; p < NSPLIT - 1; p++) {
    uint4 a = *(const uint4*)(Opart + (size_t)p * 8388608u + i);
    v0 += blo(a.x); v1 += bhi(a.x); v2 += blo(a.y); v3 += bhi(a.y);
    v4 += blo(a.z); v5 += bhi(a.z); v6 += blo(a.w); v7 += bhi(a.w);
  }
  uint4 o;
  o.x = pack_bf16(v0 * linv, v1 * linv);
  o.y = pack_bf16(v2 * linv, v3 * linv);
  o.z = pack_bf16(v4 * linv, v5 * linv);
  o.w = pack_bf16(v6 * linv, v7 * linv);
  *(uint4*)(ao + i) = o;
}

extern "C" void kernel_launch(void* const* d_in, const int* in_sizes, int n_in,
                              void* d_out, int out_size, void* d_ws, size_t ws_size,
                              hipStream_t stream) {
  const float* x    = (const float*)d_in[0];
  const float* Wq   = (const float*)d_in[1];
  const float* Wk   = (const float*)d_in[2];
  const float* Wv   = (const float*)d_in[3];
  const float* Wo   = (const float*)d_in[4];
  const float* gain = (const float*)d_in[5];
  const float* cosT = (const float*)d_in[6];
  const float* sinT = (const float*)d_in[7];
  float* out = (float*)d_out;

  unsigned short* ws = (unsigned short*)d_ws;  // elem offsets (bf16)
  unsigned short* blob = ws;                   // x|Wq|Wk|Wv|Wo bf16
  unsigned short* xb  = blob;
  unsigned short* Wqb = blob + 8388608u;
  unsigned short* Wkb = blob + 9437184u;
  unsigned short* Wvb = blob + 9568256u;
  unsigned short* Wob = blob + 9699328u;
  unsigned short* q   = ws + 10747904u;        // 8388608 elems
  unsigned short* kk  = ws + 19136512u;        // 1048576
  unsigned short* v   = ws + 20185088u;        // 1048576
  unsigned short* vT  = ws + 21233664u;        // 1048576
  unsigned short* ao  = xb;                    // alias: xb dead after gemm_qkv
  unsigned short* Opart = ws + 22282240u;      // 1 x 8388608 elems (NSPLIT=2)
  float* l2 = (float*)((char*)d_ws + 61341696u);   // 2 x 65536 f32
  const size_t need2 = 61865984ull;

  // 0. f32 -> bf16 convert of all GEMM operands
  cvt_kernel<<<5248, 256, 0, stream>>>(x, Wq, Wk, Wv, Wo, blob);
  // 1. fused QKV projection (M=8192, K=1024, N=1024+128+128)
  gemm_qkv_kernel<<<dim3(64, 10), 256, 0, stream>>>(xb, Wqb, Wkb, Wvb, q, kk, v);
  // 2. prep: vtrans (256 blocks) + vectorized RoPE (2304 blocks)
  prep_kernel<<<2560, 256, 0, stream>>>(q, kk, v, vT, cosT, sinT, gain);
  // 3. flash attention + combine. NSPLIT=2: 512 blocks = 2/CU co-resident;
  //    2 tiles per barrier epoch (quad-buffered LDS).
  if (ws_size >= need2) {
    attn_kernel<2><<<dim3(16, 8, 4), 256, 0, stream>>>(q, kk, vT, ao, Opart, l2);
    combine_kernel<2><<<4096, 256, 0, stream>>>(Opart, l2, ao);
  } else {
    attn_kernel<1><<<dim3(8, 8, 4), 256, 0, stream>>>(q, kk, vT, ao, Opart, l2);
  }
  // 4. output projection (bf16 -> f32 out)
  gemm_out_kernel<<<dim3(64, 8), 256, 0, stream>>>(ao, Wob, out);
}

// Round 11
// 230.748 us; speedup vs baseline: 1.1656x; 1.1656x over previous
//
#include <hip/hip_runtime.h>
#include <hip/hip_bf16.h>

// Problem constants (B=4, T=2048, D=1024, NH=8, NKV=1, HD=128)
#define B_ 4
#define T_ 2048
#define D_ 1024
#define NH_ 8
#define HD_ 128

typedef short short8 __attribute__((ext_vector_type(8)));    // 8 bf16 (4 VGPRs) MFMA frag
typedef float floatx4 __attribute__((ext_vector_type(4)));   // 16x16 MFMA accumulator
typedef float floatx16 __attribute__((ext_vector_type(16))); // 32x32 MFMA accumulator

#if __has_builtin(__builtin_amdgcn_exp2f)
#define EXP2F __builtin_amdgcn_exp2f
#else
#define EXP2F exp2f
#endif
#if __has_builtin(__builtin_amdgcn_rcpf)
#define RCPF __builtin_amdgcn_rcpf
#else
__device__ __forceinline__ float RCPF(float x) { return 1.f / x; }
#endif

// async global->LDS 16B copy (m97 lever); LDS dest must be wave-uniform base
// + lane*16B, which the GEMM staging pattern satisfies by construction.
#if __has_builtin(__builtin_amdgcn_global_load_lds)
#define G2L(gp, lp)                                                        \
  __builtin_amdgcn_global_load_lds(                                        \
      (const __attribute__((address_space(1))) unsigned int*)(gp),         \
      (__attribute__((address_space(3))) unsigned int*)(lp), 16, 0, 0)
#else
#define G2L(gp, lp) (*(uint4*)(lp) = *(const uint4*)(gp))
#endif

__device__ __forceinline__ unsigned short f2b(float f) {
  union { float fl; unsigned int i; } v; v.fl = f;
  unsigned int r = v.i + 0x7fffu + ((v.i >> 16) & 1u);  // RNE, non-NaN inputs
  return (unsigned short)(r >> 16);
}
// pack two f32 -> two bf16 (round-to-nearest): low16 = a, high16 = b
__device__ __forceinline__ unsigned int pack_bf16(float a, float b) {
  unsigned int ua = __float_as_uint(a) + 0x8000u;
  unsigned int ub = __float_as_uint(b) + 0x8000u;
  return (ua >> 16) | (ub & 0xffff0000u);
}
__device__ __forceinline__ float blo(unsigned int u) { return __uint_as_float(u << 16); }
__device__ __forceinline__ float bhi(unsigned int u) { return __uint_as_float(u & 0xffff0000u); }

// ---------------------------------------------------------------------------
// One-shot f32 -> bf16 convert of x|Wq|Wk|Wv|Wo into a contiguous bf16 blob.
// ---------------------------------------------------------------------------
__global__ __launch_bounds__(256) void cvt_kernel(
    const float* __restrict__ x,  const float* __restrict__ wq,
    const float* __restrict__ wk, const float* __restrict__ wv,
    const float* __restrict__ wo, unsigned short* __restrict__ dst)
{
  size_t i = ((size_t)blockIdx.x * 256 + threadIdx.x) * 8;
  const float* src; size_t off;
  if      (i <  8388608u) { src = x;  off = i; }
  else if (i <  9437184u) { src = wq; off = i - 8388608u; }
  else if (i <  9568256u) { src = wk; off = i - 9437184u; }
  else if (i <  9699328u) { src = wv; off = i - 9568256u; }
  else                    { src = wo; off = i - 9699328u; }
  float4 a = *(const float4*)(src + off);
  float4 b = *(const float4*)(src + off + 4);
  uint4 o;
  o.x = pack_bf16(a.x, a.y); o.y = pack_bf16(a.z, a.w);
  o.z = pack_bf16(b.x, b.y); o.w = pack_bf16(b.z, b.w);
  *(uint4*)(dst + i) = o;
}

// ---------------------------------------------------------------------------
// 128x128-tile GEMM body, C = A * B^T, K=1024, bf16 in, fp32 accumulate.
// ROUND-4 single-buffer schedule (proven best; explicit dbuf (r6), fused
// RoPE (r7), fused combine (r8) all regressed).
// ---------------------------------------------------------------------------
template <bool C_F32>
__device__ __forceinline__ void gemm_body_1024(
    const unsigned short* __restrict__ Arow0,
    const unsigned short* __restrict__ Btile,
    void* __restrict__ Cb, int ldC)
{
  __shared__ unsigned short As[128 * 32];
  __shared__ unsigned short Bs[128 * 32];
  const int tid = threadIdx.x;
  const int lane = tid & 63;
  const int w = tid >> 6;
  const int wr = w >> 1, wc = w & 1;
  const int l15 = lane & 15, quad = lane >> 4;

  const unsigned short* a_src = Arow0 + (size_t)(tid >> 2) * 1024 + (tid & 3) * 8;
  const unsigned short* b_src = Btile + (size_t)(tid >> 2) * 1024 + (tid & 3) * 8;
  unsigned short* a_dst = &As[(tid >> 2) * 32 + (tid & 3) * 8];
  unsigned short* b_dst = &Bs[(tid >> 2) * 32 + (tid & 3) * 8];

  floatx4 zero = {0.f, 0.f, 0.f, 0.f};
  floatx4 acc[4][4];
#pragma unroll
  for (int i = 0; i < 4; i++)
#pragma unroll
    for (int j = 0; j < 4; j++) acc[i][j] = zero;

  for (int k0 = 0; k0 < 1024; k0 += 32) {
    __syncthreads();
    G2L(a_src + k0,         a_dst);
    G2L(a_src + 65536 + k0, a_dst + 2048);   // +64 rows
    G2L(b_src + k0,         b_dst);
    G2L(b_src + 65536 + k0, b_dst + 2048);
    __syncthreads();                          // drains vmcnt incl. lds-DMA
    short8 af[4], bfr[4];
#pragma unroll
    for (int i = 0; i < 4; i++)
      af[i] = *(const short8*)&As[(wr * 64 + i * 16 + l15) * 32 + quad * 8];
#pragma unroll
    for (int j = 0; j < 4; j++)
      bfr[j] = *(const short8*)&Bs[(wc * 64 + j * 16 + l15) * 32 + quad * 8];
#pragma unroll
    for (int i = 0; i < 4; i++)
#pragma unroll
      for (int j = 0; j < 4; j++)
        acc[i][j] = __builtin_amdgcn_mfma_f32_16x16x32_bf16(af[i], bfr[j], acc[i][j], 0, 0, 0);
  }
  // epilogue: C row = quad*4+reg, col = lane&15 (verified m89/m91 layout)
#pragma unroll
  for (int i = 0; i < 4; i++)
#pragma unroll
    for (int j = 0; j < 4; j++)
#pragma unroll
      for (int r = 0; r < 4; r++) {
        size_t off = (size_t)(wr * 64 + i * 16 + quad * 4 + r) * ldC + wc * 64 + j * 16 + l15;
        if (C_F32) ((float*)Cb)[off] = acc[i][j][r];
        else ((unsigned short*)Cb)[off] = f2b(acc[i][j][r]);
      }
}

// ---------------------------------------------------------------------------
// ROUND 18: T1 XCD-aware swizzle on both GEMMs. Default round-robin
// dispatch spreads the 10 (resp. 8) blocks sharing one A-row-panel across
// all 8 per-XCD L2s -> the 16.7MB A operand is re-fetched from HBM per
// XCD. 1D grid + m157 swizzle (work = (bid%8)*chunk + bid/8, work ordered
// bx-major) gives each XCD a contiguous set of 8 bx rows x all by: per-XCD
// fetch ~2MB A + ~2.5MB B, L2-resident. 640%8==0 / 512%8==0 -> bijective.
// ---------------------------------------------------------------------------
__global__ __launch_bounds__(256) void gemm_qkv_kernel(
    const unsigned short* __restrict__ x,
    const unsigned short* __restrict__ Wq,
    const unsigned short* __restrict__ Wk,
    const unsigned short* __restrict__ Wv,
    unsigned short* __restrict__ q,
    unsigned short* __restrict__ k,
    unsigned short* __restrict__ v)
{
  const int bid = blockIdx.x;                 // 0..639
  const int s = (bid & 7) * 80 + (bid >> 3);  // XCD-chunked work index
  const int bx = s / 10, by = s % 10;         // XCD owns 8 bx rows, all by
  const unsigned short* Btile;
  unsigned short* C;
  int ldC, col0;
  if (by < 8) { Btile = Wq + (size_t)by * 128 * 1024; C = q; ldC = 1024; col0 = by * 128; }
  else if (by == 8) { Btile = Wk; C = k; ldC = 128; col0 = 0; }
  else { Btile = Wv; C = v; ldC = 128; col0 = 0; }
  gemm_body_1024<false>(x + (size_t)bx * 128 * 1024, Btile,
                        C + (size_t)bx * 128 * ldC + col0, ldC);
}

__global__ __launch_bounds__(256) void gemm_out_kernel(
    const unsigned short* __restrict__ ao,
    const unsigned short* __restrict__ Wo,
    float* __restrict__ out)
{
  const int bid = blockIdx.x;                 // 0..511
  const int s = (bid & 7) * 64 + (bid >> 3);
  const int bx = s >> 3, by = s & 7;          // XCD owns 8 bx rows, all by
  gemm_body_1024<true>(ao + (size_t)bx * 128 * 1024, Wo + (size_t)by * 128 * 1024,
                       out + (size_t)bx * 128 * 1024 + by * 128, 1024);
}

// ---------------------------------------------------------------------------
// prep: fused vtrans (blocks 0..255) + vectorized RoPE (8 pairs/thread).
// q gets gain*(1/sqrt(HD))/SOFTCAP folded in. (Round-4 proven version.)
// ---------------------------------------------------------------------------
__global__ __launch_bounds__(256) void prep_kernel(
    unsigned short* __restrict__ q,
    unsigned short* __restrict__ k,
    const unsigned short* __restrict__ v,
    unsigned short* __restrict__ vT,
    const float* __restrict__ cosT,
    const float* __restrict__ sinT,
    const float* __restrict__ gain)
{
  __shared__ unsigned short tile[32 * 136];
  const int tid = threadIdx.x;
  if (blockIdx.x < 256) {
    const int b = blockIdx.x >> 6, t0 = (blockIdx.x & 63) * 32;
    for (int u = tid; u < 512; u += 256) {
      int r = u >> 4, c = u & 15;
      *(uint4*)&tile[r * 136 + c * 8] =
          *(const uint4*)(v + ((size_t)(b * T_ + t0 + r)) * 128 + c * 8);
    }
    __syncthreads();
    for (int u = tid; u < 512; u += 256) {
      int d = u >> 2, c = u & 3;
      short8 val;
#pragma unroll
      for (int j = 0; j < 8; j++) val[j] = (short)tile[(c * 8 + j) * 136 + d];
      *(short8*)(vT + ((size_t)(b * 128 + d)) * T_ + t0 + c * 8) = val;
    }
    return;
  }
  int idx = (blockIdx.x - 256) * 256 + tid;   // 0 .. 589823
  unsigned short* ptr;
  size_t base;
  int t, j;
  float g;
  if (idx < 524288) {                         // q: (bt, h, dim-octet j)
    j = idx & 7;
    int h = (idx >> 3) & 7;
    int bt = idx >> 6;
    t = bt & (T_ - 1);
    base = (size_t)bt * 1024 + h * 128 + j * 8;
    ptr = q;
    g = gain[h] * 0.0029462782549439484f;     // (1/sqrt(128))/30
  } else {                                    // k
    int id = idx - 524288;
    j = id & 7;
    int bt = id >> 3;
    t = bt & (T_ - 1);
    base = (size_t)bt * 128 + j * 8;
    ptr = k;
    g = 1.f;
  }
  float4 ca = *(const float4*)&cosT[t * 64 + j * 8];
  float4 cb = *(const float4*)&cosT[t * 64 + j * 8 + 4];
  float4 sa = *(const float4*)&sinT[t * 64 + j * 8];
  float4 sb = *(const float4*)&sinT[t * 64 + j * 8 + 4];
  uint4 lo = *(const uint4*)(ptr + base);
  uint4 hi = *(const uint4*)(ptr + base + 64);
  uint4 olo, ohi;
  {
    float a0 = blo(lo.x), a1 = bhi(lo.x), b0 = blo(hi.x), b1 = bhi(hi.x);
    olo.x = pack_bf16((a0 * ca.x - b0 * sa.x) * g, (a1 * ca.y - b1 * sa.y) * g);
    ohi.x = pack_bf16((a0 * sa.x + b0 * ca.x) * g, (a1 * sa.y + b1 * ca.y) * g);
  }
  {
    float a0 = blo(lo.y), a1 = bhi(lo.y), b0 = blo(hi.y), b1 = bhi(hi.y);
    olo.y = pack_bf16((a0 * ca.z - b0 * sa.z) * g, (a1 * ca.w - b1 * sa.w) * g);
    ohi.y = pack_bf16((a0 * sa.z + b0 * ca.z) * g, (a1 * sa.w + b1 * ca.w) * g);
  }
  {
    float a0 = blo(lo.z), a1 = bhi(lo.z), b0 = blo(hi.z), b1 = bhi(hi.z);
    olo.z = pack_bf16((a0 * cb.x - b0 * sb.x) * g, (a1 * cb.y - b1 * sb.y) * g);
    ohi.z = pack_bf16((a0 * sb.x + b0 * cb.x) * g, (a1 * sb.y + b1 * cb.y) * g);
  }
  {
    float a0 = blo(lo.w), a1 = bhi(lo.w), b0 = blo(hi.w), b1 = bhi(hi.w);
    olo.w = pack_bf16((a0 * cb.z - b0 * sb.z) * g, (a1 * cb.w - b1 * sb.w) * g);
    ohi.w = pack_bf16((a0 * sb.z + b0 * cb.z) * g, (a1 * sb.w + b1 * cb.w) * g);
  }
  *(uint4*)(ptr + base) = olo;
  *(uint4*)(ptr + base + 64) = ohi;
}

// ---------------------------------------------------------------------------
// Flash attention — round-9 best (attn 72.9us within the proven 71-76
// plateau; 8 structural variants bracket it). 32x32x16 MFMA, 32 q-rows/
// wave, LDS K/V double-buffer, T14 issue-early/write-late staging,
// in-register softmax + 4 permlane32_swap, NSPLIT=2 (512 blocks = 2/CU).
// (Round-10's quad-buffer pair-epoch spilled to scratch and regressed 3x;
// the plateau is accepted as this structure's floor.)
// ---------------------------------------------------------------------------
template <int NSPLIT>
__global__ __launch_bounds__(256, 3) void attn_kernel(
    const unsigned short* __restrict__ q,
    const unsigned short* __restrict__ k,
    const unsigned short* __restrict__ vT,
    unsigned short* __restrict__ ao,
    unsigned short* __restrict__ Opart,
    float* __restrict__ lbuf)
{
  __shared__ unsigned short Ks[2][16 * 264];   // [buf][dimgroup d][key*8 + j]
  __shared__ unsigned short Vts[2][128 * 40];  // [buf][dim][key]

  const int h = blockIdx.y, b = blockIdx.z;
  const int pr   = blockIdx.x / NSPLIT;        // 0..7 (chunk-pair index)
  const int part = blockIdx.x % NSPLIT;
  const int tid = threadIdx.x, lane = tid & 63, w = tid >> 6;
  const int q32 = lane & 31, hi = lane >> 5;

  // K staging: key = tid>>4 (+16), dimgroup = tid&15
  const unsigned short* ksrc =
      k + (size_t)b * T_ * 128 + (size_t)(tid >> 4) * 128 + (tid & 15) * 8;
  const int koff0 = (tid & 15) * 264 + (tid >> 4) * 8;
  const int koff1 = koff0 + 16 * 8;
  // V staging: row = tid>>2 (+64), col8 = tid&3
  const unsigned short* vsrc =
      vT + (size_t)b * 128 * T_ + (size_t)(tid >> 2) * T_ + (tid & 3) * 8;
  const int voff0 = (tid >> 2) * 40 + (tid & 3) * 8;
  const int voff1 = voff0 + 64 * 40;

  for (int pass = 0; pass < 2; pass++) {
    const int qblock = pass ? (15 - pr) : pr;  // 128-row q-chunk index
    const int qw = qblock * 128 + w * 32;      // wave's first q-row
    const int nkt = 4 * qblock + 4;
    const int base = nkt / NSPLIT, rem = nkt % NSPLIT;
    const int ktBeg = part * base + (part < rem ? part : rem);
    const int ktEnd = ktBeg + base + (part < rem ? 1 : 0);

    // Q B-frags: lane holds Q[q=qw+q32][dim = c*16 + 8*hi + j], c=0..7
    short8 qf[8];
    {
      const unsigned short* qrow =
          q + ((size_t)(b * T_ + qw + q32) * NH_ + h) * HD_ + hi * 8;
#pragma unroll
      for (int c = 0; c < 8; c++) qf[c] = *(const short8*)(qrow + c * 16);
    }

    float l_i = 0.f;
    floatx16 acc[4];
#pragma unroll
    for (int dt = 0; dt < 4; dt++)
#pragma unroll
      for (int r = 0; r < 16; r++) acc[dt][r] = 0.f;

    // pass-start barrier: previous pass/prologue reads done before reuse
    __syncthreads();
    // prologue: stage tile ktBeg into buf[ktBeg&1]
    {
      uint4 kr0 = *(const uint4*)(ksrc + (size_t)ktBeg * 4096);
      uint4 kr1 = *(const uint4*)(ksrc + (size_t)ktBeg * 4096 + 2048);
      uint4 vr0 = *(const uint4*)(vsrc + ktBeg * 32);
      uint4 vr1 = *(const uint4*)(vsrc + (size_t)64 * T_ + ktBeg * 32);
      unsigned short* kb = Ks[ktBeg & 1];
      unsigned short* vb = Vts[ktBeg & 1];
      *(uint4*)(kb + koff0) = kr0; *(uint4*)(kb + koff1) = kr1;
      *(uint4*)(vb + voff0) = vr0; *(uint4*)(vb + voff1) = vr1;
    }

    for (int kt = ktBeg; kt < ktEnd; kt++) {
      __syncthreads();                 // publishes buf[kt&1]
      // prefetch tile kt+1 AFTER the barrier (T14): latency hides under
      // compute; write-late store consumes it before the next barrier.
      uint4 kr0, kr1, vr0, vr1;
      const bool more = (kt + 1 < ktEnd);
      if (more) {
        kr0 = *(const uint4*)(ksrc + (size_t)(kt + 1) * 4096);
        kr1 = *(const uint4*)(ksrc + (size_t)(kt + 1) * 4096 + 2048);
        vr0 = *(const uint4*)(vsrc + (kt + 1) * 32);
        vr1 = *(const uint4*)(vsrc + (size_t)64 * T_ + (kt + 1) * 32);
      }

      if (kt * 32 <= qw + 31) {        // wave-uniform causal skip
        const unsigned short* KsC = Ks[kt & 1];
        const unsigned short* VtC = Vts[kt & 1];
        // S^T = K Q^T, one 32x32 tile, K-dim = 128 = 8 chained MFMA32
        floatx16 st;
#pragma unroll
        for (int r = 0; r < 16; r++) st[r] = 0.f;
#pragma unroll
        for (int c = 0; c < 8; c++) {
          short8 kf = *(const short8*)&KsC[(2 * c + hi) * 264 + q32 * 8];
          st = __builtin_amdgcn_mfma_f32_32x32x16_bf16(kf, qf[c], st, 0, 0, 0);
        }
        // fused softcap+softmax numerator (fixed m=30), all in registers
        float rs = 0.f;
        unsigned int A[8];
        if (kt * 32 + 31 <= qw) {      // fully unmasked (most iterations)
          float pv[16];
#pragma unroll
          for (int r = 0; r < 16; r++) {
            float s = st[r];
            float e = EXP2F(2.8853901f * s);
            float u = RCPF(e + 1.f);
            float p = EXP2F(-86.561707f * u);
            pv[r] = p;
            rs += p;
          }
#pragma unroll
          for (int m = 0; m < 8; m++) A[m] = pack_bf16(pv[2 * m], pv[2 * m + 1]);
        } else {                       // boundary tile: apply causal mask
          const int qrow = qw + q32;
          float pv[16];
#pragma unroll
          for (int r = 0; r < 16; r++) {
            float s = st[r];
            float e = EXP2F(2.8853901f * s);
            float u = RCPF(e + 1.f);
            float p = EXP2F(-86.561707f * u);
            int key = kt * 32 + (r & 3) + 8 * (r >> 2) + 4 * hi;
            p = (key <= qrow) ? p : 0.f;
            pv[r] = p;
            rs += p;
          }
#pragma unroll
          for (int m = 0; m < 8; m++) A[m] = pack_bf16(pv[2 * m], pv[2 * m + 1]);
        }
        // build PV B-frags via 4 permlane32 swaps (round-12 derivation)
        unsigned int a0 = A[0], a1 = A[1], a2 = A[2], a3 = A[3];
        unsigned int a4 = A[4], a5 = A[5], a6 = A[6], a7 = A[7];
        asm("v_permlane32_swap_b32 %0, %1" : "+v"(a0), "+v"(a2));
        asm("v_permlane32_swap_b32 %0, %1" : "+v"(a1), "+v"(a3));
        asm("v_permlane32_swap_b32 %0, %1" : "+v"(a4), "+v"(a6));
        asm("v_permlane32_swap_b32 %0, %1" : "+v"(a5), "+v"(a7));
        uint4 u0; u0.x = a0; u0.y = a1; u0.z = a2; u0.w = a3;
        uint4 u1; u1.x = a4; u1.y = a5; u1.z = a6; u1.w = a7;
        short8 pf0 = *(short8*)&u0;   // keys 0-15 B-frag
        short8 pf1 = *(short8*)&u1;   // keys 16-31 B-frag
        l_i += rs + __shfl_xor(rs, 32);
        // O^T += V^T P^T: 4 d-tiles x 2 key-halves
#pragma unroll
        for (int dt = 0; dt < 4; dt++) {
          short8 v0 = *(const short8*)&VtC[(dt * 32 + q32) * 40 + hi * 8];
          short8 v1 = *(const short8*)&VtC[(dt * 32 + q32) * 40 + 16 + hi * 8];
          acc[dt] = __builtin_amdgcn_mfma_f32_32x32x16_bf16(v0, pf0, acc[dt], 0, 0, 0);
          acc[dt] = __builtin_amdgcn_mfma_f32_32x32x16_bf16(v1, pf1, acc[dt], 0, 0, 0);
        }
      }

      if (more) {                      // write-late: stage kt+1 after compute
        unsigned short* kb = Ks[(kt + 1) & 1];
        unsigned short* vb = Vts[(kt + 1) & 1];
        *(uint4*)(kb + koff0) = kr0; *(uint4*)(kb + koff1) = kr1;
        *(uint4*)(vb + voff0) = vr0; *(uint4*)(vb + voff1) = vr1;
      }
    }

    // epilogue: lane q=q32; acc[dt][r] = O^T[dim=dt*32+(r&3)+8(r>>2)+4hi][q]
    {
      const size_t rowidx = (size_t)(b * T_ + qw + q32) * NH_ + h;
      if (NSPLIT == 1) {
        float linv = 1.f / l_i;
        unsigned short* aop = ao + rowidx * HD_;
#pragma unroll
        for (int dt = 0; dt < 4; dt++)
#pragma unroll
          for (int rg = 0; rg < 4; rg++) {
            uint2 o;
            o.x = pack_bf16(acc[dt][4 * rg + 0] * linv, acc[dt][4 * rg + 1] * linv);
            o.y = pack_bf16(acc[dt][4 * rg + 2] * linv, acc[dt][4 * rg + 3] * linv);
            *(uint2*)(aop + dt * 32 + rg * 8 + hi * 4) = o;
          }
      } else {
        unsigned short* dst =
            ((part == NSPLIT - 1) ? ao : Opart + (size_t)part * 8388608u) +
            rowidx * HD_;
#pragma unroll
        for (int dt = 0; dt < 4; dt++)
#pragma unroll
          for (int rg = 0; rg < 4; rg++) {
            uint2 o;
            o.x = pack_bf16(acc[dt][4 * rg + 0], acc[dt][4 * rg + 1]);
            o.y = pack_bf16(acc[dt][4 * rg + 2], acc[dt][4 * rg + 3]);
            *(uint2*)(dst + dt * 32 + rg * 8 + hi * 4) = o;
          }
        if (hi == 0) lbuf[(size_t)part * 65536u + rowidx] = l_i;
      }
    }
  }
}

// ao = (sum of partials + ao) / (sum of l), 8 bf16 elems per thread
template <int NSPLIT>
__global__ __launch_bounds__(256) void combine_kernel(
    const unsigned short* __restrict__ Opart,
    const float* __restrict__ lbuf,
    unsigned short* __restrict__ ao)
{
  size_t i = ((size_t)blockIdx.x * 256 + threadIdx.x) * 8;
  size_t r = i >> 7;                          // (b*T+t)*NH+h
  float ls = 0.f;
#pragma unroll
  for (int p = 0; p < NSPLIT; p++) ls += lbuf[(size_t)p * 65536u + r];
  float linv = RCPF(ls);
  uint4 c = *(const uint4*)(ao + i);
  float v0 = blo(c.x), v1 = bhi(c.x), v2 = blo(c.y), v3 = bhi(c.y);
  float v4 = blo(c.z), v5 = bhi(c.z), v6 = blo(c.w), v7 = bhi(c.w);
#pragma unroll
  for (int p = 0; p < NSPLIT - 1; p++) {
    uint4 a = *(const uint4*)(Opart + (size_t)p * 8388608u + i);
    v0 += blo(a.x); v1 += bhi(a.x); v2 += blo(a.y); v3 += bhi(a.y);
    v4 += blo(a.z); v5 += bhi(a.z); v6 += blo(a.w); v7 += bhi(a.w);
  }
  uint4 o;
  o.x = pack_bf16(v0 * linv, v1 * linv);
  o.y = pack_bf16(v2 * linv, v3 * linv);
  o.z = pack_bf16(v4 * linv, v5 * linv);
  o.w = pack_bf16(v6 * linv, v7 * linv);
  *(uint4*)(ao + i) = o;
}

extern "C" void kernel_launch(void* const* d_in, const int* in_sizes, int n_in,
                              void* d_out, int out_size, void* d_ws, size_t ws_size,
                              hipStream_t stream) {
  const float* x    = (const float*)d_in[0];
  const float* Wq   = (const float*)d_in[1];
  const float* Wk   = (const float*)d_in[2];
  const float* Wv   = (const float*)d_in[3];
  const float* Wo   = (const float*)d_in[4];
  const float* gain = (const float*)d_in[5];
  const float* cosT = (const float*)d_in[6];
  const float* sinT = (const float*)d_in[7];
  float* out = (float*)d_out;

  unsigned short* ws = (unsigned short*)d_ws;  // elem offsets (bf16)
  unsigned short* blob = ws;                   // x|Wq|Wk|Wv|Wo bf16
  unsigned short* xb  = blob;
  unsigned short* Wqb = blob + 8388608u;
  unsigned short* Wkb = blob + 9437184u;
  unsigned short* Wvb = blob + 9568256u;
  unsigned short* Wob = blob + 9699328u;
  unsigned short* q   = ws + 10747904u;        // 8388608 elems
  unsigned short* kk  = ws + 19136512u;        // 1048576
  unsigned short* v   = ws + 20185088u;        // 1048576
  unsigned short* vT  = ws + 21233664u;        // 1048576
  unsigned short* ao  = xb;                    // alias: xb dead after gemm_qkv
  unsigned short* Opart = ws + 22282240u;      // 1 x 8388608 elems (NSPLIT=2)
  float* l2 = (float*)((char*)d_ws + 61341696u);   // 2 x 65536 f32
  const size_t need2 = 61865984ull;

  // 0. f32 -> bf16 convert of all GEMM operands
  cvt_kernel<<<5248, 256, 0, stream>>>(x, Wq, Wk, Wv, Wo, blob);
  // 1. fused QKV projection (M=8192, K=1024, N=1024+128+128), XCD-swizzled
  gemm_qkv_kernel<<<640, 256, 0, stream>>>(xb, Wqb, Wkb, Wvb, q, kk, v);
  // 2. prep: vtrans (256 blocks) + vectorized RoPE (2304 blocks)
  prep_kernel<<<2560, 256, 0, stream>>>(q, kk, v, vT, cosT, sinT, gain);
  // 3. flash attention + combine (round-9 best config)
  if (ws_size >= need2) {
    attn_kernel<2><<<dim3(16, 8, 4), 256, 0, stream>>>(q, kk, vT, ao, Opart, l2);
    combine_kernel<2><<<4096, 256, 0, stream>>>(Opart, l2, ao);
  } else {
    attn_kernel<1><<<dim3(8, 8, 4), 256, 0, stream>>>(q, kk, vT, ao, Opart, l2);
  }
  // 4. output projection (bf16 -> f32 out), XCD-swizzled
  gemm_out_kernel<<<512, 256, 0, stream>>>(ao, Wob, out);
}

// Round 12
// 226.996 us; speedup vs baseline: 1.1849x; 1.0165x over previous
//
#include <hip/hip_runtime.h>
#include <hip/hip_bf16.h>

// Problem constants (B=4, T=2048, D=1024, NH=8, NKV=1, HD=128)
#define B_ 4
#define T_ 2048
#define D_ 1024
#define NH_ 8
#define HD_ 128

typedef short short8 __attribute__((ext_vector_type(8)));    // 8 bf16 (4 VGPRs) MFMA frag
typedef float floatx4 __attribute__((ext_vector_type(4)));   // 16x16 MFMA accumulator
typedef float floatx16 __attribute__((ext_vector_type(16))); // 32x32 MFMA accumulator

#if __has_builtin(__builtin_amdgcn_exp2f)
#define EXP2F __builtin_amdgcn_exp2f
#else
#define EXP2F exp2f
#endif
#if __has_builtin(__builtin_amdgcn_rcpf)
#define RCPF __builtin_amdgcn_rcpf
#else
__device__ __forceinline__ float RCPF(float x) { return 1.f / x; }
#endif

// async global->LDS 16B copy (m97 lever); LDS dest must be wave-uniform base
// + lane*16B, which the GEMM staging pattern satisfies by construction.
#if __has_builtin(__builtin_amdgcn_global_load_lds)
#define G2L(gp, lp)                                                        \
  __builtin_amdgcn_global_load_lds(                                        \
      (const __attribute__((address_space(1))) unsigned int*)(gp),         \
      (__attribute__((address_space(3))) unsigned int*)(lp), 16, 0, 0)
#else
#define G2L(gp, lp) (*(uint4*)(lp) = *(const uint4*)(gp))
#endif

__device__ __forceinline__ unsigned short f2b(float f) {
  union { float fl; unsigned int i; } v; v.fl = f;
  unsigned int r = v.i + 0x7fffu + ((v.i >> 16) & 1u);  // RNE, non-NaN inputs
  return (unsigned short)(r >> 16);
}
// pack two f32 -> two bf16 (round-to-nearest): low16 = a, high16 = b
__device__ __forceinline__ unsigned int pack_bf16(float a, float b) {
  unsigned int ua = __float_as_uint(a) + 0x8000u;
  unsigned int ub = __float_as_uint(b) + 0x8000u;
  return (ua >> 16) | (ub & 0xffff0000u);
}
__device__ __forceinline__ float blo(unsigned int u) { return __uint_as_float(u << 16); }
__device__ __forceinline__ float bhi(unsigned int u) { return __uint_as_float(u & 0xffff0000u); }

// ---------------------------------------------------------------------------
// One-shot f32 -> bf16 convert of x|Wq|Wk|Wv|Wo into a contiguous bf16 blob.
// ---------------------------------------------------------------------------
__global__ __launch_bounds__(256) void cvt_kernel(
    const float* __restrict__ x,  const float* __restrict__ wq,
    const float* __restrict__ wk, const float* __restrict__ wv,
    const float* __restrict__ wo, unsigned short* __restrict__ dst)
{
  size_t i = ((size_t)blockIdx.x * 256 + threadIdx.x) * 8;
  const float* src; size_t off;
  if      (i <  8388608u) { src = x;  off = i; }
  else if (i <  9437184u) { src = wq; off = i - 8388608u; }
  else if (i <  9568256u) { src = wk; off = i - 9437184u; }
  else if (i <  9699328u) { src = wv; off = i - 9568256u; }
  else                    { src = wo; off = i - 9699328u; }
  float4 a = *(const float4*)(src + off);
  float4 b = *(const float4*)(src + off + 4);
  uint4 o;
  o.x = pack_bf16(a.x, a.y); o.y = pack_bf16(a.z, a.w);
  o.z = pack_bf16(b.x, b.y); o.w = pack_bf16(b.z, b.w);
  *(uint4*)(dst + i) = o;
}

// ---------------------------------------------------------------------------
// 128x128-tile GEMM body, C = A * B^T, K=1024, bf16 in, fp32 accumulate.
// ROUND 19: BK=64 — stage TWO 32-wide panels per barrier pair. The proven
// round-4 schedule pays the drain-at-issue tax (G2L -> barrier's vmcnt(0))
// once per 32-wide k-step = 64 barriers/block. Here each outer step issues
// 8 G2L (two panels, each panel keeping the exact lane-contiguous LDS dest
// mapping G2L requires: panel p at elem offset p*4096), drains once, then
// runs 32 MFMAs (two sequential panel sub-steps). Barrier/drain events
// halve (64->32), in-flight loads per drain double. LDS 16->32KB (not the
// occupancy binder; registers are). Everything else byte-identical.
// ---------------------------------------------------------------------------
template <bool C_F32>
__device__ __forceinline__ void gemm_body_1024(
    const unsigned short* __restrict__ Arow0,
    const unsigned short* __restrict__ Btile,
    void* __restrict__ Cb, int ldC)
{
  __shared__ unsigned short As[2 * 128 * 32];   // two 32-wide column panels
  __shared__ unsigned short Bs[2 * 128 * 32];
  const int tid = threadIdx.x;
  const int lane = tid & 63;
  const int w = tid >> 6;
  const int wr = w >> 1, wc = w & 1;
  const int l15 = lane & 15, quad = lane >> 4;

  const unsigned short* a_src = Arow0 + (size_t)(tid >> 2) * 1024 + (tid & 3) * 8;
  const unsigned short* b_src = Btile + (size_t)(tid >> 2) * 1024 + (tid & 3) * 8;
  const int dstoff = (tid >> 2) * 32 + (tid & 3) * 8;

  floatx4 zero = {0.f, 0.f, 0.f, 0.f};
  floatx4 acc[4][4];
#pragma unroll
  for (int i = 0; i < 4; i++)
#pragma unroll
    for (int j = 0; j < 4; j++) acc[i][j] = zero;

  for (int k0 = 0; k0 < 1024; k0 += 64) {
    __syncthreads();
    // panel 0: cols k0..k0+31 ; panel 1: cols k0+32..k0+63
    G2L(a_src + k0,              &As[dstoff]);
    G2L(a_src + 65536 + k0,      &As[dstoff + 2048]);    // +64 rows
    G2L(a_src + k0 + 32,         &As[4096 + dstoff]);
    G2L(a_src + 65536 + k0 + 32, &As[4096 + dstoff + 2048]);
    G2L(b_src + k0,              &Bs[dstoff]);
    G2L(b_src + 65536 + k0,      &Bs[dstoff + 2048]);
    G2L(b_src + k0 + 32,         &Bs[4096 + dstoff]);
    G2L(b_src + 65536 + k0 + 32, &Bs[4096 + dstoff + 2048]);
    __syncthreads();                          // drains vmcnt incl. lds-DMA
#pragma unroll
    for (int p = 0; p < 2; p++) {
      short8 af[4], bfr[4];
#pragma unroll
      for (int i = 0; i < 4; i++)
        af[i] = *(const short8*)&As[p * 4096 + (wr * 64 + i * 16 + l15) * 32 + quad * 8];
#pragma unroll
      for (int j = 0; j < 4; j++)
        bfr[j] = *(const short8*)&Bs[p * 4096 + (wc * 64 + j * 16 + l15) * 32 + quad * 8];
#pragma unroll
      for (int i = 0; i < 4; i++)
#pragma unroll
        for (int j = 0; j < 4; j++)
          acc[i][j] = __builtin_amdgcn_mfma_f32_16x16x32_bf16(af[i], bfr[j], acc[i][j], 0, 0, 0);
    }
  }
  // epilogue: C row = quad*4+reg, col = lane&15 (verified m89/m91 layout)
#pragma unroll
  for (int i = 0; i < 4; i++)
#pragma unroll
    for (int j = 0; j < 4; j++)
#pragma unroll
      for (int r = 0; r < 4; r++) {
        size_t off = (size_t)(wr * 64 + i * 16 + quad * 4 + r) * ldC + wc * 64 + j * 16 + l15;
        if (C_F32) ((float*)Cb)[off] = acc[i][j][r];
        else ((unsigned short*)Cb)[off] = f2b(acc[i][j][r]);
      }
}

// ---------------------------------------------------------------------------
// T1 XCD-aware swizzle on both GEMMs (round-11, measured win): each XCD
// owns a contiguous set of bx rows x all by -> A-panel L2-resident per XCD.
// 640%8==0 / 512%8==0 -> bijective.
// ---------------------------------------------------------------------------
__global__ __launch_bounds__(256) void gemm_qkv_kernel(
    const unsigned short* __restrict__ x,
    const unsigned short* __restrict__ Wq,
    const unsigned short* __restrict__ Wk,
    const unsigned short* __restrict__ Wv,
    unsigned short* __restrict__ q,
    unsigned short* __restrict__ k,
    unsigned short* __restrict__ v)
{
  const int bid = blockIdx.x;                 // 0..639
  const int s = (bid & 7) * 80 + (bid >> 3);  // XCD-chunked work index
  const int bx = s / 10, by = s % 10;         // XCD owns 8 bx rows, all by
  const unsigned short* Btile;
  unsigned short* C;
  int ldC, col0;
  if (by < 8) { Btile = Wq + (size_t)by * 128 * 1024; C = q; ldC = 1024; col0 = by * 128; }
  else if (by == 8) { Btile = Wk; C = k; ldC = 128; col0 = 0; }
  else { Btile = Wv; C = v; ldC = 128; col0 = 0; }
  gemm_body_1024<false>(x + (size_t)bx * 128 * 1024, Btile,
                        C + (size_t)bx * 128 * ldC + col0, ldC);
}

__global__ __launch_bounds__(256) void gemm_out_kernel(
    const unsigned short* __restrict__ ao,
    const unsigned short* __restrict__ Wo,
    float* __restrict__ out)
{
  const int bid = blockIdx.x;                 // 0..511
  const int s = (bid & 7) * 64 + (bid >> 3);
  const int bx = s >> 3, by = s & 7;          // XCD owns 8 bx rows, all by
  gemm_body_1024<true>(ao + (size_t)bx * 128 * 1024, Wo + (size_t)by * 128 * 1024,
                       out + (size_t)bx * 128 * 1024 + by * 128, 1024);
}

// ---------------------------------------------------------------------------
// prep: fused vtrans (blocks 0..255) + vectorized RoPE (8 pairs/thread).
// q gets gain*(1/sqrt(HD))/SOFTCAP folded in. (Round-4 proven version.)
// ---------------------------------------------------------------------------
__global__ __launch_bounds__(256) void prep_kernel(
    unsigned short* __restrict__ q,
    unsigned short* __restrict__ k,
    const unsigned short* __restrict__ v,
    unsigned short* __restrict__ vT,
    const float* __restrict__ cosT,
    const float* __restrict__ sinT,
    const float* __restrict__ gain)
{
  __shared__ unsigned short tile[32 * 136];
  const int tid = threadIdx.x;
  if (blockIdx.x < 256) {
    const int b = blockIdx.x >> 6, t0 = (blockIdx.x & 63) * 32;
    for (int u = tid; u < 512; u += 256) {
      int r = u >> 4, c = u & 15;
      *(uint4*)&tile[r * 136 + c * 8] =
          *(const uint4*)(v + ((size_t)(b * T_ + t0 + r)) * 128 + c * 8);
    }
    __syncthreads();
    for (int u = tid; u < 512; u += 256) {
      int d = u >> 2, c = u & 3;
      short8 val;
#pragma unroll
      for (int j = 0; j < 8; j++) val[j] = (short)tile[(c * 8 + j) * 136 + d];
      *(short8*)(vT + ((size_t)(b * 128 + d)) * T_ + t0 + c * 8) = val;
    }
    return;
  }
  int idx = (blockIdx.x - 256) * 256 + tid;   // 0 .. 589823
  unsigned short* ptr;
  size_t base;
  int t, j;
  float g;
  if (idx < 524288) {                         // q: (bt, h, dim-octet j)
    j = idx & 7;
    int h = (idx >> 3) & 7;
    int bt = idx >> 6;
    t = bt & (T_ - 1);
    base = (size_t)bt * 1024 + h * 128 + j * 8;
    ptr = q;
    g = gain[h] * 0.0029462782549439484f;     // (1/sqrt(128))/30
  } else {                                    // k
    int id = idx - 524288;
    j = id & 7;
    int bt = id >> 3;
    t = bt & (T_ - 1);
    base = (size_t)bt * 128 + j * 8;
    ptr = k;
    g = 1.f;
  }
  float4 ca = *(const float4*)&cosT[t * 64 + j * 8];
  float4 cb = *(const float4*)&cosT[t * 64 + j * 8 + 4];
  float4 sa = *(const float4*)&sinT[t * 64 + j * 8];
  float4 sb = *(const float4*)&sinT[t * 64 + j * 8 + 4];
  uint4 lo = *(const uint4*)(ptr + base);
  uint4 hi = *(const uint4*)(ptr + base + 64);
  uint4 olo, ohi;
  {
    float a0 = blo(lo.x), a1 = bhi(lo.x), b0 = blo(hi.x), b1 = bhi(hi.x);
    olo.x = pack_bf16((a0 * ca.x - b0 * sa.x) * g, (a1 * ca.y - b1 * sa.y) * g);
    ohi.x = pack_bf16((a0 * sa.x + b0 * ca.x) * g, (a1 * sa.y + b1 * ca.y) * g);
  }
  {
    float a0 = blo(lo.y), a1 = bhi(lo.y), b0 = blo(hi.y), b1 = bhi(hi.y);
    olo.y = pack_bf16((a0 * ca.z - b0 * sa.z) * g, (a1 * ca.w - b1 * sa.w) * g);
    ohi.y = pack_bf16((a0 * sa.z + b0 * ca.z) * g, (a1 * sa.w + b1 * ca.w) * g);
  }
  {
    float a0 = blo(lo.z), a1 = bhi(lo.z), b0 = blo(hi.z), b1 = bhi(hi.z);
    olo.z = pack_bf16((a0 * cb.x - b0 * sb.x) * g, (a1 * cb.y - b1 * sb.y) * g);
    ohi.z = pack_bf16((a0 * sb.x + b0 * cb.x) * g, (a1 * sb.y + b1 * cb.y) * g);
  }
  {
    float a0 = blo(lo.w), a1 = bhi(lo.w), b0 = blo(hi.w), b1 = bhi(hi.w);
    olo.w = pack_bf16((a0 * cb.z - b0 * sb.z) * g, (a1 * cb.w - b1 * sb.w) * g);
    ohi.w = pack_bf16((a0 * sb.z + b0 * cb.z) * g, (a1 * sb.w + b1 * cb.w) * g);
  }
  *(uint4*)(ptr + base) = olo;
  *(uint4*)(ptr + base + 64) = ohi;
}

// ---------------------------------------------------------------------------
// Flash attention — round-9/11 best (attn 71.8-72.9us; 8 structural
// variants bracket the 71-76 plateau; accepted floor). 32x32x16 MFMA,
// 32 q-rows/wave, LDS K/V double-buffer, T14 issue-early/write-late
// staging, in-register softmax + 4 permlane32_swap, NSPLIT=2 (512 blocks).
// ---------------------------------------------------------------------------
template <int NSPLIT>
__global__ __launch_bounds__(256, 3) void attn_kernel(
    const unsigned short* __restrict__ q,
    const unsigned short* __restrict__ k,
    const unsigned short* __restrict__ vT,
    unsigned short* __restrict__ ao,
    unsigned short* __restrict__ Opart,
    float* __restrict__ lbuf)
{
  __shared__ unsigned short Ks[2][16 * 264];   // [buf][dimgroup d][key*8 + j]
  __shared__ unsigned short Vts[2][128 * 40];  // [buf][dim][key]

  const int h = blockIdx.y, b = blockIdx.z;
  const int pr   = blockIdx.x / NSPLIT;        // 0..7 (chunk-pair index)
  const int part = blockIdx.x % NSPLIT;
  const int tid = threadIdx.x, lane = tid & 63, w = tid >> 6;
  const int q32 = lane & 31, hi = lane >> 5;

  // K staging: key = tid>>4 (+16), dimgroup = tid&15
  const unsigned short* ksrc =
      k + (size_t)b * T_ * 128 + (size_t)(tid >> 4) * 128 + (tid & 15) * 8;
  const int koff0 = (tid & 15) * 264 + (tid >> 4) * 8;
  const int koff1 = koff0 + 16 * 8;
  // V staging: row = tid>>2 (+64), col8 = tid&3
  const unsigned short* vsrc =
      vT + (size_t)b * 128 * T_ + (size_t)(tid >> 2) * T_ + (tid & 3) * 8;
  const int voff0 = (tid >> 2) * 40 + (tid & 3) * 8;
  const int voff1 = voff0 + 64 * 40;

  for (int pass = 0; pass < 2; pass++) {
    const int qblock = pass ? (15 - pr) : pr;  // 128-row q-chunk index
    const int qw = qblock * 128 + w * 32;      // wave's first q-row
    const int nkt = 4 * qblock + 4;
    const int base = nkt / NSPLIT, rem = nkt % NSPLIT;
    const int ktBeg = part * base + (part < rem ? part : rem);
    const int ktEnd = ktBeg + base + (part < rem ? 1 : 0);

    // Q B-frags: lane holds Q[q=qw+q32][dim = c*16 + 8*hi + j], c=0..7
    short8 qf[8];
    {
      const unsigned short* qrow =
          q + ((size_t)(b * T_ + qw + q32) * NH_ + h) * HD_ + hi * 8;
#pragma unroll
      for (int c = 0; c < 8; c++) qf[c] = *(const short8*)(qrow + c * 16);
    }

    float l_i = 0.f;
    floatx16 acc[4];
#pragma unroll
    for (int dt = 0; dt < 4; dt++)
#pragma unroll
      for (int r = 0; r < 16; r++) acc[dt][r] = 0.f;

    // pass-start barrier: previous pass/prologue reads done before reuse
    __syncthreads();
    // prologue: stage tile ktBeg into buf[ktBeg&1]
    {
      uint4 kr0 = *(const uint4*)(ksrc + (size_t)ktBeg * 4096);
      uint4 kr1 = *(const uint4*)(ksrc + (size_t)ktBeg * 4096 + 2048);
      uint4 vr0 = *(const uint4*)(vsrc + ktBeg * 32);
      uint4 vr1 = *(const uint4*)(vsrc + (size_t)64 * T_ + ktBeg * 32);
      unsigned short* kb = Ks[ktBeg & 1];
      unsigned short* vb = Vts[ktBeg & 1];
      *(uint4*)(kb + koff0) = kr0; *(uint4*)(kb + koff1) = kr1;
      *(uint4*)(vb + voff0) = vr0; *(uint4*)(vb + voff1) = vr1;
    }

    for (int kt = ktBeg; kt < ktEnd; kt++) {
      __syncthreads();                 // publishes buf[kt&1]
      // prefetch tile kt+1 AFTER the barrier (T14): latency hides under
      // compute; write-late store consumes it before the next barrier.
      uint4 kr0, kr1, vr0, vr1;
      const bool more = (kt + 1 < ktEnd);
      if (more) {
        kr0 = *(const uint4*)(ksrc + (size_t)(kt + 1) * 4096);
        kr1 = *(const uint4*)(ksrc + (size_t)(kt + 1) * 4096 + 2048);
        vr0 = *(const uint4*)(vsrc + (kt + 1) * 32);
        vr1 = *(const uint4*)(vsrc + (size_t)64 * T_ + (kt + 1) * 32);
      }

      if (kt * 32 <= qw + 31) {        // wave-uniform causal skip
        const unsigned short* KsC = Ks[kt & 1];
        const unsigned short* VtC = Vts[kt & 1];
        // S^T = K Q^T, one 32x32 tile, K-dim = 128 = 8 chained MFMA32
        floatx16 st;
#pragma unroll
        for (int r = 0; r < 16; r++) st[r] = 0.f;
#pragma unroll
        for (int c = 0; c < 8; c++) {
          short8 kf = *(const short8*)&KsC[(2 * c + hi) * 264 + q32 * 8];
          st = __builtin_amdgcn_mfma_f32_32x32x16_bf16(kf, qf[c], st, 0, 0, 0);
        }
        // fused softcap+softmax numerator (fixed m=30), all in registers
        float rs = 0.f;
        unsigned int A[8];
        if (kt * 32 + 31 <= qw) {      // fully unmasked (most iterations)
          float pv[16];
#pragma unroll
          for (int r = 0; r < 16; r++) {
            float s = st[r];
            float e = EXP2F(2.8853901f * s);
            float u = RCPF(e + 1.f);
            float p = EXP2F(-86.561707f * u);
            pv[r] = p;
            rs += p;
          }
#pragma unroll
          for (int m = 0; m < 8; m++) A[m] = pack_bf16(pv[2 * m], pv[2 * m + 1]);
        } else {                       // boundary tile: apply causal mask
          const int qrow = qw + q32;
          float pv[16];
#pragma unroll
          for (int r = 0; r < 16; r++) {
            float s = st[r];
            float e = EXP2F(2.8853901f * s);
            float u = RCPF(e + 1.f);
            float p = EXP2F(-86.561707f * u);
            int key = kt * 32 + (r & 3) + 8 * (r >> 2) + 4 * hi;
            p = (key <= qrow) ? p : 0.f;
            pv[r] = p;
            rs += p;
          }
#pragma unroll
          for (int m = 0; m < 8; m++) A[m] = pack_bf16(pv[2 * m], pv[2 * m + 1]);
        }
        // build PV B-frags via 4 permlane32 swaps (round-12 derivation)
        unsigned int a0 = A[0], a1 = A[1], a2 = A[2], a3 = A[3];
        unsigned int a4 = A[4], a5 = A[5], a6 = A[6], a7 = A[7];
        asm("v_permlane32_swap_b32 %0, %1" : "+v"(a0), "+v"(a2));
        asm("v_permlane32_swap_b32 %0, %1" : "+v"(a1), "+v"(a3));
        asm("v_permlane32_swap_b32 %0, %1" : "+v"(a4), "+v"(a6));
        asm("v_permlane32_swap_b32 %0, %1" : "+v"(a5), "+v"(a7));
        uint4 u0; u0.x = a0; u0.y = a1; u0.z = a2; u0.w = a3;
        uint4 u1; u1.x = a4; u1.y = a5; u1.z = a6; u1.w = a7;
        short8 pf0 = *(short8*)&u0;   // keys 0-15 B-frag
        short8 pf1 = *(short8*)&u1;   // keys 16-31 B-frag
        l_i += rs + __shfl_xor(rs, 32);
        // O^T += V^T P^T: 4 d-tiles x 2 key-halves
#pragma unroll
        for (int dt = 0; dt < 4; dt++) {
          short8 v0 = *(const short8*)&VtC[(dt * 32 + q32) * 40 + hi * 8];
          short8 v1 = *(const short8*)&VtC[(dt * 32 + q32) * 40 + 16 + hi * 8];
          acc[dt] = __builtin_amdgcn_mfma_f32_32x32x16_bf16(v0, pf0, acc[dt], 0, 0, 0);
          acc[dt] = __builtin_amdgcn_mfma_f32_32x32x16_bf16(v1, pf1, acc[dt], 0, 0, 0);
        }
      }

      if (more) {                      // write-late: stage kt+1 after compute
        unsigned short* kb = Ks[(kt + 1) & 1];
        unsigned short* vb = Vts[(kt + 1) & 1];
        *(uint4*)(kb + koff0) = kr0; *(uint4*)(kb + koff1) = kr1;
        *(uint4*)(vb + voff0) = vr0; *(uint4*)(vb + voff1) = vr1;
      }
    }

    // epilogue: lane q=q32; acc[dt][r] = O^T[dim=dt*32+(r&3)+8(r>>2)+4hi][q]
    {
      const size_t rowidx = (size_t)(b * T_ + qw + q32) * NH_ + h;
      if (NSPLIT == 1) {
        float linv = 1.f / l_i;
        unsigned short* aop = ao + rowidx * HD_;
#pragma unroll
        for (int dt = 0; dt < 4; dt++)
#pragma unroll
          for (int rg = 0; rg < 4; rg++) {
            uint2 o;
            o.x = pack_bf16(acc[dt][4 * rg + 0] * linv, acc[dt][4 * rg + 1] * linv);
            o.y = pack_bf16(acc[dt][4 * rg + 2] * linv, acc[dt][4 * rg + 3] * linv);
            *(uint2*)(aop + dt * 32 + rg * 8 + hi * 4) = o;
          }
      } else {
        unsigned short* dst =
            ((part == NSPLIT - 1) ? ao : Opart + (size_t)part * 8388608u) +
            rowidx * HD_;
#pragma unroll
        for (int dt = 0; dt < 4; dt++)
#pragma unroll
          for (int rg = 0; rg < 4; rg++) {
            uint2 o;
            o.x = pack_bf16(acc[dt][4 * rg + 0], acc[dt][4 * rg + 1]);
            o.y = pack_bf16(acc[dt][4 * rg + 2], acc[dt][4 * rg + 3]);
            *(uint2*)(dst + dt * 32 + rg * 8 + hi * 4) = o;
          }
        if (hi == 0) lbuf[(size_t)part * 65536u + rowidx] = l_i;
      }
    }
  }
}

// ao = (sum of partials + ao) / (sum of l), 8 bf16 elems per thread
template <int NSPLIT>
__global__ __launch_bounds__(256) void combine_kernel(
    const unsigned short* __restrict__ Opart,
    const float* __restrict__ lbuf,
    unsigned short* __restrict__ ao)
{
  size_t i = ((size_t)blockIdx.x * 256 + threadIdx.x) * 8;
  size_t r = i >> 7;                          // (b*T+t)*NH+h
  float ls = 0.f;
#pragma unroll
  for (int p = 0; p < NSPLIT; p++) ls += lbuf[(size_t)p * 65536u + r];
  float linv = RCPF(ls);
  uint4 c = *(const uint4*)(ao + i);
  float v0 = blo(c.x), v1 = bhi(c.x), v2 = blo(c.y), v3 = bhi(c.y);
  float v4 = blo(c.z), v5 = bhi(c.z), v6 = blo(c.w), v7 = bhi(c.w);
#pragma unroll
  for (int p = 0; p < NSPLIT - 1; p++) {
    uint4 a = *(const uint4*)(Opart + (size_t)p * 8388608u + i);
    v0 += blo(a.x); v1 += bhi(a.x); v2 += blo(a.y); v3 += bhi(a.y);
    v4 += blo(a.z); v5 += bhi(a.z); v6 += blo(a.w); v7 += bhi(a.w);
  }
  uint4 o;
  o.x = pack_bf16(v0 * linv, v1 * linv);
  o.y = pack_bf16(v2 * linv, v3 * linv);
  o.z = pack_bf16(v4 * linv, v5 * linv);
  o.w = pack_bf16(v6 * linv, v7 * linv);
  *(uint4*)(ao + i) = o;
}

extern "C" void kernel_launch(void* const* d_in, const int* in_sizes, int n_in,
                              void* d_out, int out_size, void* d_ws, size_t ws_size,
                              hipStream_t stream) {
  const float* x    = (const float*)d_in[0];
  const float* Wq   = (const float*)d_in[1];
  const float* Wk   = (const float*)d_in[2];
  const float* Wv   = (const float*)d_in[3];
  const float* Wo   = (const float*)d_in[4];
  const float* gain = (const float*)d_in[5];
  const float* cosT = (const float*)d_in[6];
  const float* sinT = (const float*)d_in[7];
  float* out = (float*)d_out;

  unsigned short* ws = (unsigned short*)d_ws;  // elem offsets (bf16)
  unsigned short* blob = ws;                   // x|Wq|Wk|Wv|Wo bf16
  unsigned short* xb  = blob;
  unsigned short* Wqb = blob + 8388608u;
  unsigned short* Wkb = blob + 9437184u;
  unsigned short* Wvb = blob + 9568256u;
  unsigned short* Wob = blob + 9699328u;
  unsigned short* q   = ws + 10747904u;        // 8388608 elems
  unsigned short* kk  = ws + 19136512u;        // 1048576
  unsigned short* v   = ws + 20185088u;        // 1048576
  unsigned short* vT  = ws + 21233664u;        // 1048576
  unsigned short* ao  = xb;                    // alias: xb dead after gemm_qkv
  unsigned short* Opart = ws + 22282240u;      // 1 x 8388608 elems (NSPLIT=2)
  float* l2 = (float*)((char*)d_ws + 61341696u);   // 2 x 65536 f32
  const size_t need2 = 61865984ull;

  // 0. f32 -> bf16 convert of all GEMM operands
  cvt_kernel<<<5248, 256, 0, stream>>>(x, Wq, Wk, Wv, Wo, blob);
  // 1. fused QKV projection (M=8192, K=1024, N=1024+128+128), XCD-swizzled
  gemm_qkv_kernel<<<640, 256, 0, stream>>>(xb, Wqb, Wkb, Wvb, q, kk, v);
  // 2. prep: vtrans (256 blocks) + vectorized RoPE (2304 blocks)
  prep_kernel<<<2560, 256, 0, stream>>>(q, kk, v, vT, cosT, sinT, gain);
  // 3. flash attention + combine (round-9 best config)
  if (ws_size >= need2) {
    attn_kernel<2><<<dim3(16, 8, 4), 256, 0, stream>>>(q, kk, vT, ao, Opart, l2);
    combine_kernel<2><<<4096, 256, 0, stream>>>(Opart, l2, ao);
  } else {
    attn_kernel<1><<<dim3(8, 8, 4), 256, 0, stream>>>(q, kk, vT, ao, Opart, l2);
  }
  // 4. output projection (bf16 -> f32 out), XCD-swizzled
  gemm_out_kernel<<<512, 256, 0, stream>>>(ao, Wob, out);
}